// Round 7
// baseline (85.354 us; speedup 1.0000x reference)
//
#include <hip/hip_runtime.h>
#include <cstdint>

// DirectAU loss: align(u,i) + 0.5*(uniform(u) + uniform(i)), T=2, GAMMA=1.
// N=8192 rows, D=64.
//   k1: normalize rows (fp32), write bf16 copies to ws, per-block align partial.
//   k2: 256x256-tile X@X^T via mfma_f32_16x16x32_bf16. B-stripe (32 KB) staged
//       to LDS in fragment order; A-fragments direct from global. 256-thread
//       blocks -> 5 blocks/CU -> ALL 1056 tiles co-resident (no serial tail,
//       which R6 analysis showed was doubling gram's wall time). Fused
//       exp2+sum epilogue, per-block partial, no atomics.
//   k3: reduce partials + combine -> d_out[0].
// Harness floor: ws re-poison fill = 268 MB @ ~80% HBM peak (~42us) per timed
// iteration — immovable, and it sweeps L2/L3 cold every iteration.

#define NROWS 8192
#define DIM 64
#define NT2 32                            // 8192/256 tiles per side
#define GRAM_SLOTS (NT2 * (NT2 + 1))      // 32*33 = 1056
#define K1_BLOCKS 1024                    // 4 waves/block * 2 rows/wave

static constexpr float EXP_SCALE = 5.770780163555852f; // 2*T*log2(e) = 4*log2(e)
static constexpr float EPS_F = 1e-8f;

typedef __bf16 bf16x8 __attribute__((ext_vector_type(8)));
typedef float f32x4 __attribute__((ext_vector_type(4)));

__device__ __forceinline__ unsigned short f32_to_bf16_rn(float f) {
    union { float f; uint32_t u; } c; c.f = f;
    uint32_t u = c.u;
    uint32_t r = u + 0x7FFFu + ((u >> 16) & 1u);
    return (unsigned short)(r >> 16);
}

// ---- kernel 1: normalize + bf16 cast + per-block alignment partial ---------
__global__ void __launch_bounds__(256) normalize_align_kernel(
    const float* __restrict__ user, const float* __restrict__ item,
    unsigned short* __restrict__ xu, unsigned short* __restrict__ xi,
    float* __restrict__ pa)
{
    const int wave = threadIdx.x >> 6;
    const int lane = threadIdx.x & 63;
    const int wid  = blockIdx.x * 4 + wave;   // 0..4095, 2 rows per wave

    float asum = 0.0f;
    #pragma unroll
    for (int r = 0; r < 2; ++r) {
        const int idx = (wid * 2 + r) * DIM + lane;   // wave spans one row
        float u = user[idx];
        float v = item[idx];
        float su = u * u, sv = v * v;
        #pragma unroll
        for (int m = 1; m < 64; m <<= 1) {
            su += __shfl_xor(su, m, 64);
            sv += __shfl_xor(sv, m, 64);
        }
        float iu = rsqrtf(su); iu = iu * (1.5f - 0.5f * su * iu * iu);
        float iv = rsqrtf(sv); iv = iv * (1.5f - 0.5f * sv * iv * iv);
        float un = u * iu, vn = v * iv;
        xu[idx] = f32_to_bf16_rn(un);
        xi[idx] = f32_to_bf16_rn(vn);
        float d = un - vn;
        asum += d * d;
    }
    #pragma unroll
    for (int m = 1; m < 64; m <<= 1) asum += __shfl_xor(asum, m, 64);
    __shared__ float ws4[4];
    if (lane == 0) ws4[wave] = asum;
    __syncthreads();
    if (threadIdx.x == 0) pa[blockIdx.x] = ws4[0] + ws4[1] + ws4[2] + ws4[3];
}

// ---- kernel 2: 256x256 gram tile + exp + per-block partial -----------------
// 256 threads = 4 waves; wave w owns row-16-tiles 4w..4w+3 of the A-stripe.
// B-stripe fragment-order LDS layout per 16-row tile: ushort idx =
//   tile*1024 + c*128 + r16*8  (c = k/8 in 0..7; 2 KB/tile, 32 KB total).
// Operand read: ds_read_b128 at tile*1024 + ks*512 + lane*8 — contiguous
// 1 KB per wave, conflict-free. wsum aliased into lds after the compute
// barrier to keep LDS block exactly 32 KB (5 blocks/CU).
__global__ void __launch_bounds__(256, 5) gram_exp_kernel(
    const unsigned short* __restrict__ xu,
    const unsigned short* __restrict__ xi,
    float* __restrict__ pg)
{
    const int bx = blockIdx.x, by = blockIdx.y;
    const unsigned short* __restrict__ X;
    int bi, bj;
    if (by < NT2) {
        if (by >= bx) { X = xu; bi = bx; bj = by; }
        else          { X = xi; bi = by; bj = bx; }
    } else            { X = xi; bi = bx; bj = bx; }
    const bool diag = (bi == bj);

    __shared__ unsigned short lds[16384];      // exactly 32 KB
    float* wsum = reinterpret_cast<float*>(lds);  // reused post-barrier

    const int wave = threadIdx.x >> 6;
    const int lane = threadIdx.x & 63;

    // A fragments straight from global (issued early, overlap staging).
    bf16x8 a[4][2];
    {
        const int arow = bi * 256 + wave * 64 + (lane & 15);
        const int acol = (lane >> 4) * 8;
        #pragma unroll
        for (int rb = 0; rb < 4; ++rb)
            #pragma unroll
            for (int ks = 0; ks < 2; ++ks)
                a[rb][ks] = *reinterpret_cast<const bf16x8*>(
                    X + (arow + rb * 16) * DIM + acol + ks * 32);
    }

    // Stage B-stripe (rows bj*256..+256), coalesced global -> fragment-order LDS.
    {
        const int base = bj * 256;
        #pragma unroll
        for (int i = 0; i < 8; ++i) {
            int n = i * 256 + threadIdx.x;       // 16B-chunk id, 0..2047
            int r = n >> 3, c = n & 7;
            bf16x8 v = *reinterpret_cast<const bf16x8*>(X + (base + r) * DIM + c * 8);
            int di = (r >> 4) * 1024 + c * 128 + (r & 15) * 8;
            *reinterpret_cast<bf16x8*>(&lds[di]) = v;
        }
    }
    __syncthreads();

    float l0 = 0.0f, l1 = 0.0f;
    #pragma unroll
    for (int cb = 0; cb < 16; ++cb) {
        bf16x8 b0 = *reinterpret_cast<const bf16x8*>(&lds[cb * 1024 + lane * 8]);
        bf16x8 b1 = *reinterpret_cast<const bf16x8*>(&lds[cb * 1024 + 512 + lane * 8]);
        #pragma unroll
        for (int rb = 0; rb < 4; ++rb) {
            f32x4 c = {0.f, 0.f, 0.f, 0.f};
            c = __builtin_amdgcn_mfma_f32_16x16x32_bf16(a[rb][0], b0, c, 0, 0, 0);
            c = __builtin_amdgcn_mfma_f32_16x16x32_bf16(a[rb][1], b1, c, 0, 0, 0);
            // exp(-T*max(2-2g,0)) = min(exp2(g*S - S), 1); clamp only needed
            // where g>1 possible (diagonal tiles).
            #pragma unroll
            for (int e = 0; e < 4; ++e) {
                float ex = __builtin_amdgcn_exp2f(fmaf(c[e], EXP_SCALE, -EXP_SCALE));
                if (diag) ex = fminf(ex, 1.0f);
                if (e & 1) l1 += ex; else l0 += ex;
            }
        }
    }

    float local = l0 + l1;
    #pragma unroll
    for (int m = 1; m < 64; m <<= 1) local += __shfl_xor(local, m, 64);
    __syncthreads();                 // all waves done reading lds for MFMA
    if (lane == 0) wsum[wave] = local;
    __syncthreads();
    if (threadIdx.x == 0) {
        float t = wsum[0] + wsum[1] + wsum[2] + wsum[3];
        pg[by * NT2 + bx] = diag ? t : 2.0f * t;
    }
}

// ---- kernel 3: reduce partials + combine -----------------------------------
__global__ void __launch_bounds__(256) final_kernel(
    const float* __restrict__ pa, const float* __restrict__ pg,
    float* __restrict__ out)
{
    float a = 0.f, su = 0.f, si = 0.f;
    for (int s = threadIdx.x; s < K1_BLOCKS; s += 256) a += pa[s];
    for (int s = threadIdx.x; s < GRAM_SLOTS; s += 256) {
        int bx = s & (NT2 - 1), by = s >> 5;
        bool is_item = (by == NT2) || (by < bx);
        float v = pg[s];
        if (is_item) si += v; else su += v;
    }
    #pragma unroll
    for (int m = 1; m < 64; m <<= 1) {
        a  += __shfl_xor(a,  m, 64);
        su += __shfl_xor(su, m, 64);
        si += __shfl_xor(si, m, 64);
    }
    __shared__ float r[12];
    const int wave = threadIdx.x >> 6, lane = threadIdx.x & 63;
    if (lane == 0) { r[wave] = a; r[4 + wave] = su; r[8 + wave] = si; }
    __syncthreads();
    if (threadIdx.x == 0) {
        float A  = r[0] + r[1] + r[2]  + r[3];
        float SU = r[4] + r[5] + r[6]  + r[7];
        float SI = r[8] + r[9] + r[10] + r[11];
        const float n = (float)NROWS;
        const float denom = n * (n - 1.0f);
        out[0] = A / n + 0.5f * (logf((SU - n) / denom + EPS_F)
                               + logf((SI - n) / denom + EPS_F));
    }
}

extern "C" void kernel_launch(void* const* d_in, const int* in_sizes, int n_in,
                              void* d_out, int out_size, void* d_ws, size_t ws_size,
                              hipStream_t stream)
{
    const float* user = (const float*)d_in[0];
    const float* item = (const float*)d_in[1];

    unsigned short* xu = (unsigned short*)d_ws;                 // 1 MB
    unsigned short* xi = xu + (size_t)NROWS * DIM;              // 1 MB
    float* pa = (float*)(xi + (size_t)NROWS * DIM);             // 1024 floats
    float* pg = pa + K1_BLOCKS;                                 // 1056 floats

    normalize_align_kernel<<<K1_BLOCKS, 256, 0, stream>>>(user, item, xu, xi, pa);
    gram_exp_kernel<<<dim3(NT2, NT2 + 1), 256, 0, stream>>>(xu, xi, pg);
    final_kernel<<<1, 256, 0, stream>>>(pa, pg, (float*)d_out);
}